// Round 9
// baseline (298.529 us; speedup 1.0000x reference)
//
#include <hip/hip_runtime.h>

// Round 9 = Round 8 resubmission (container infra failure, experiment unrun).
// Occupancy A/B: 8 waves/SIMD via 2 channels/lane.
// Evidence chain: store-only = 39.3us (floor), fp32 FLOP time ~22us
// (irreducible), full kernel = 65us = ADDITIVE -> VMEM/VALU overlap is the
// missing piece. Only occupancy ever moved the number (R4 8w/CU=80us,
// R5 16w/CU=65us). This round: 32 waves/CU. The 84-VGPR W fragment capped
// us at 4 waves/SIMD; halving to 2 c/lane (wfv=42 VGPR, total ~58<=64)
// unlocks 8 waves/SIMD. 512-thread blocks (4 row-quarters x 2 c-halves),
// same ~34KB LDS -> 4 blocks/CU, 1024 blocks = one fully-resident round.

#define B_N   8
#define S_N   2048
#define K_N   21
#define L_N   16
#define CM_N  256
#define SCHUNK 128
#define CHUNKS (S_N / SCHUNK)   // 16
#define LGRP   2                 // layers per block, time-multiplexed
#define NLG    (L_N / LGRP)      // 8
#define WSTRIDE 258              // even -> 8B-aligned float2 rows, bank-spread
#define NT     512               // threads/block (8 waves)

typedef float vfloat4 __attribute__((ext_vector_type(4)));
typedef float vfloat2 __attribute__((ext_vector_type(2)));

__device__ __forceinline__ void stage_wt(float (*wt)[WSTRIDE],
                                         const float* __restrict__ W,
                                         int l, int tid) {
    const vfloat4* wb4 = (const vfloat4*)(W + (size_t)l * CM_N * K_N);
    for (int i4 = tid; i4 < CM_N * K_N / 4; i4 += NT) {
        vfloat4 v = wb4[i4];
        int e0 = i4 * 4;
#pragma unroll
        for (int j = 0; j < 4; ++j) {
            int e = e0 + j;
            int c = e / K_N, k = e - c * K_N;
            wt[k][c] = v[j];
        }
    }
}

// LDS: 12.3KB (xs) + 21.2KB (wt) = 33.5KB -> 4 blocks/CU = 32 waves/CU.
// launch_bounds(512, 8): 8 waves/EU -> compiler must fit VGPR <= 64.
__global__ __launch_bounds__(NT, 8) void pssm_proj_kernel(
    const float* __restrict__ x,     // [B,S,K]
    const float* __restrict__ W,     // [L,CM,K]
    const float* __restrict__ bias,  // [L,CM]
    float* __restrict__ out)         // [B,L,S,CM]
{
    __shared__ float xs[SCHUNK][24];
    __shared__ float wt[K_N][WSTRIDE];

    const int tid   = threadIdx.x;
    const int bx    = blockIdx.x;
    const int chunk = bx % CHUNKS;
    const int lg    = (bx / CHUNKS) % NLG;
    const int b     = bx / (CHUNKS * NLG);
    const int s0    = chunk * SCHUNK;
    const int l0    = lg * LGRP;

    // ---- stage x chunk -> LDS (dwordx4 loads, scatter into padded rows) ----
    const vfloat4* xb4 = (const vfloat4*)(x + ((size_t)b * S_N + s0) * K_N);
    for (int i4 = tid; i4 < SCHUNK * K_N / 4; i4 += NT) {
        vfloat4 v = xb4[i4];
        int e0 = i4 * 4;
#pragma unroll
        for (int j = 0; j < 4; ++j) {
            int e = e0 + j;
            int r = e / K_N, k = e - r * K_N;
            xs[r][k] = v[j];
        }
    }

    stage_wt(wt, W, l0, tid);      // layer A weights
    __syncthreads();

    const int lane = tid & 63;
    const int wave = tid >> 6;     // 0..7
    const int half = wave & 1;     // c half: [0,128) or [128,256)
    const int rq   = wave >> 1;    // row quarter: 32 rows each
    const int c0   = half * 128 + lane * 2;

    // ---- pass A fragment: 21 float2 LDS reads (one-time) ----
    vfloat2 wfv[K_N];
#pragma unroll
    for (int k = 0; k < K_N; ++k)
        wfv[k] = *(const vfloat2*)(&wt[k][c0]);

    __syncthreads();               // wt reusable
    stage_wt(wt, W, l0 + 1, tid);  // stage B under pass A's stream

    vfloat2 bv = *(const vfloat2*)(bias + (size_t)l0 * CM_N + c0);
    vfloat2 bv2 = *(const vfloat2*)(bias + (size_t)(l0 + 1) * CM_N + c0);

    for (int pass = 0; pass < LGRP; ++pass) {
        const int l = l0 + pass;
        float* outbase = out +
            (((size_t)b * L_N + l) * S_N + s0 + rq * 32) * CM_N + c0;

        for (int r = 0; r < 32; ++r) {
            const vfloat4* xv = (const vfloat4*)(&xs[rq * 32 + r][0]);  // uniform broadcast

            float a0 = bv.x, a1 = bv.y;
#pragma unroll
            for (int kb = 0; kb < 6; ++kb) {
                vfloat4 xq = xv[kb];
#pragma unroll
                for (int e = 0; e < 4; ++e) {
                    const int k = kb * 4 + e;
                    if (k < K_N) {   // compile-time guard (K=21 < 24 pad)
                        a0 += xq[e] * wfv[k].x;
                        a1 += xq[e] * wfv[k].y;
                    }
                }
            }

            vfloat2 o = {a0, a1};
            *(vfloat2*)(outbase + (size_t)r * CM_N) = o;   // 512B/wave, coalesced
        }

        if (pass == 0) {
            __syncthreads();       // wt[B] staged by all waves
#pragma unroll
            for (int k = 0; k < K_N; ++k)
                wfv[k] = *(const vfloat2*)(&wt[k][c0]);
            bv = bv2;
        }
    }
}

extern "C" void kernel_launch(void* const* d_in, const int* in_sizes, int n_in,
                              void* d_out, int out_size, void* d_ws, size_t ws_size,
                              hipStream_t stream) {
    const float* x    = (const float*)d_in[0];
    const float* W    = (const float*)d_in[1];
    const float* bias = (const float*)d_in[2];
    float* out        = (float*)d_out;

    dim3 grid(B_N * NLG * CHUNKS);   // 1024 blocks x 512 thr = 4 blocks/CU, one round
    dim3 block(NT);
    pssm_proj_kernel<<<grid, block, 0, stream>>>(x, W, bias, out);
}